// Round 12
// baseline (102.014 us; speedup 1.0000x reference)
//
#include <hip/hip_runtime.h>
#include <hip/hip_fp16.h>

typedef __attribute__((ext_vector_type(8))) _Float16 f16x8;
typedef __attribute__((ext_vector_type(4))) float f32x4;
typedef __attribute__((ext_vector_type(4))) unsigned int u32x4;
typedef unsigned int  u32;
typedef unsigned short u16;

constexpr int B_  = 2;
constexpr int C_  = 64;
constexpr int O_  = 64;
constexpr int H_  = 128;
constexpr int W_  = 128;
constexpr int HW_ = H_ * W_;          // 16384
constexpr int NPIX_ = B_ * HW_;       // 32768
constexpr float BN_EPS_ = 1e-5f;

// LDS window: rows h-3..h+3 (7) x cols w0-3..w0+34 (38) = 266 px for a 32-px
// block; 64 u16 per pixel at swizzled layout addr = px*64 + ((seg^(px&7))*8)
// (seg = 8-u16 segment). Swizzle keeps b128 bank use even with zero padding.
// Slot 266 is the zero pixel (invalid im2col taps).
constexpr int WCOLS_ = 38;
constexpr int WPIX_  = 7 * WCOLS_;    // 266

__device__ __forceinline__ u16 f2bf(float f) {
    u32 u = __float_as_uint(f);
    u = (u + 0x7fffu + ((u >> 16) & 1u)) >> 16;   // RNE
    return (u16)u;
}
__device__ __forceinline__ float bflo(u32 u) { return __uint_as_float(u << 16); }
__device__ __forceinline__ float bfhi(u32 u) { return __uint_as_float(u & 0xffff0000u); }
__device__ __forceinline__ u16 f2h(float f) { return __half_as_ushort(__float2half(f)); }

__device__ __forceinline__ u32 swz(u32 wpx, u32 seg) {   // u16 units
    return wpx * 64u + ((seg ^ (wpx & 7u)) * 8u);
}

// ---------------------------------------------------------------------------
// prep: (1) transpose x -> xt[b][hw][c] fp16, (2) fragment-linear fp16
// weights WpF / W27F (kk = tap*64 + c).
// ---------------------------------------------------------------------------
__global__ __launch_bounds__(256)
void prep_kernel(const float* __restrict__ x, const float* __restrict__ conv_w,
                 const float* __restrict__ off_w, const float* __restrict__ mask_w,
                 u16* __restrict__ xt, u16* __restrict__ WpF, u16* __restrict__ W27F) {
    int bid = blockIdx.x, tid = threadIdx.x;
    if (bid < 512) {                        // x transpose: 64-pixel strip per block
        __shared__ u16 tile[64][66];
        int b = bid >> 8;
        int hw0 = (bid & 255) * 64;
        int c = tid >> 2, pq = (tid & 3) * 16;
        const float* src = x + (((size_t)(b * 64 + c)) << 14) + hw0 + pq;
#pragma unroll
        for (int i = 0; i < 4; i++) {
            float4 v = *(const float4*)(src + i * 4);
            tile[pq + i * 4 + 0][c] = f2h(v.x);
            tile[pq + i * 4 + 1][c] = f2h(v.y);
            tile[pq + i * 4 + 2][c] = f2h(v.z);
            tile[pq + i * 4 + 3][c] = f2h(v.w);
        }
        __syncthreads();
        int p = tid >> 2, cs = (tid & 3) * 16;
        uint4* dst = (uint4*)(xt + (((size_t)(b << 14)) + hw0 + p) * 64 + cs);
        dst[0] = *(const uint4*)&tile[p][cs];
        dst[1] = *(const uint4*)&tile[p][cs + 8];
    } else if (bid < 512 + 144) {           // WpF: 36,864 elements
        int i = (bid - 512) * 256 + tid;
        int j = i & 7, lane = (i >> 3) & 63, t = (i >> 9) & 3, s = i >> 11;
        int o = t * 16 + (lane & 15);
        int kk = s * 32 + (lane >> 4) * 8 + j;
        int tap = kk >> 6, c = kk & 63;
        WpF[i] = f2h(conv_w[(o * 64 + c) * 9 + tap]);
    } else {                                // W27F: 18,432 elements (bid 656..727)
        int i = (bid - 656) * 256 + tid;
        int j = i & 7, lane = (i >> 3) & 63, t = (i >> 9) & 1, s = i >> 10;
        int row = t * 16 + (lane & 15);
        int kk = s * 32 + (lane >> 4) * 8 + j;
        int tap = kk >> 6, c = kk & 63;
        float v = 0.f;
        if (row < 18) v = off_w[(row * 64 + c) * 9 + tap];
        else if (row < 27) v = mask_w[((row - 18) * 64 + c) * 9 + tap];
        W27F[i] = f2h(v);
    }
}

// ---------------------------------------------------------------------------
// Phase B meta (runtime tap): swizzled window corner addresses + half2 wgts.
// ---------------------------------------------------------------------------
__device__ __forceinline__ void metaBrt(const float* __restrict__ moff,
                                        const float* __restrict__ mmask,
                                        int tap, int p32, int h, int w, int cb,
                                        u32 quad, u32* qc, u32* cwp) {
    float dy = moff[(2 * tap) * 32 + p32];
    float dx = moff[(2 * tap + 1) * 32 + p32];
    float m  = mmask[tap * 32 + p32];
    float kdy = (float)(tap / 3 - 1), kdx = (float)(tap % 3 - 1);
    float py = dy + (float)h + kdy;
    float px = dx + (float)w + kdx;
    float y0 = floorf(py), x0 = floorf(px);
    float ly = py - y0, lx = px - x0, hy = 1.f - ly, hx = 1.f - lx;
    float y1 = y0 + 1.f, x1 = x0 + 1.f;
    bool vy0 = (y0 >= 0.f) && (y0 <= 127.f);
    bool vy1 = (y1 >= 0.f) && (y1 <= 127.f);
    bool vx0 = (x0 >= 0.f) && (x0 <= 127.f);
    bool vx1 = (x1 >= 0.f) && (x1 <= 127.f);
    int iy0 = (int)fminf(fmaxf(y0, 0.f), 127.f);
    int iy1 = (int)fminf(fmaxf(y1, 0.f), 127.f);
    int ix0 = (int)fminf(fmaxf(x0, 0.f), 127.f);
    int ix1 = (int)fminf(fmaxf(x1, 0.f), 127.f);
    int w00 = min(max(iy0 * WCOLS_ + ix0 - cb, 0), WPIX_ - 1);
    int w01 = min(max(iy0 * WCOLS_ + ix1 - cb, 0), WPIX_ - 1);
    int w10 = min(max(iy1 * WCOLS_ + ix0 - cb, 0), WPIX_ - 1);
    int w11 = min(max(iy1 * WCOLS_ + ix1 - cb, 0), WPIX_ - 1);
    qc[0] = swz((u32)w00, quad);
    qc[1] = swz((u32)w01, quad);
    qc[2] = swz((u32)w10, quad);
    qc[3] = swz((u32)w11, quad);
    __half2 c0 = __float2half2_rn((vy0 && vx0) ? hy * hx * m : 0.f);
    __half2 c1 = __float2half2_rn((vy0 && vx1) ? hy * lx * m : 0.f);
    __half2 c2 = __float2half2_rn((vy1 && vx0) ? ly * hx * m : 0.f);
    __half2 c3 = __float2half2_rn((vy1 && vx1) ? ly * lx * m : 0.f);
    cwp[0] = *(const u32*)&c0; cwp[1] = *(const u32*)&c1;
    cwp[2] = *(const u32*)&c2; cwp[3] = *(const u32*)&c3;
}

__device__ __forceinline__ void ld4x(const u16* __restrict__ win, const u32* qc,
                                     u32 sx, uint4* p) {
#pragma unroll
    for (int i = 0; i < 4; i++) p[i] = *(const uint4*)(win + (qc[i] ^ sx));
}

__device__ __forceinline__ f16x8 cmbH(const uint4* p, const u32* cwp) {
    const u32* a = &p[0].x; const u32* b = &p[1].x;
    const u32* c = &p[2].x; const u32* d = &p[3].x;
    __half2 cw0 = *(const __half2*)&cwp[0], cw1 = *(const __half2*)&cwp[1];
    __half2 cw2 = *(const __half2*)&cwp[2], cw3 = *(const __half2*)&cwp[3];
    u32x4 r;
#pragma unroll
    for (int i = 0; i < 4; i++) {
        __half2 t = __hmul2(*(const __half2*)&a[i], cw0);
        t = __hfma2(*(const __half2*)&b[i], cw1, t);
        t = __hfma2(*(const __half2*)&c[i], cw2, t);
        t = __hfma2(*(const __half2*)&d[i], cw3, t);
        r[i] = *(const u32*)&t;
    }
    return __builtin_bit_cast(f16x8, r);
}

// Phase B tap recursion: pA preloaded; meta+prefetch 1 tap ahead.
template<int TAP>
__device__ __forceinline__ void tapB(const u16* __restrict__ win,
                                     const float* __restrict__ moff,
                                     const float* __restrict__ mmask,
                                     const u16* __restrict__ WpFo,   // + oh*1024
                                     int p32, int h, int w, int cb, u32 quad,
                                     int lane, uint4 (&pA)[4], u32 (&q)[4],
                                     u32 (&cw)[4], f32x4 (&acc)[2]) {
    uint4 pB[4];
    ld4x(win, q, 32, pB);               // second channel half of current tap
    u32 qn[4]; u32 wn[4]; uint4 pC[4];
    if constexpr (TAP < 8) {
        metaBrt(moff, mmask, TAP + 1, p32, h, w, cb, quad, qn, wn);
        ld4x(win, qn, 0, pC);           // next tap prefetch
    }
    f16x8 sv = cmbH(pA, cw);
#pragma unroll
    for (int t = 0; t < 2; t++) {
        f16x8 af = *(const f16x8*)(WpFo + (u32)(2 * TAP) * 2048u + (u32)t * 512u + (u32)lane * 8u);
        acc[t] = __builtin_amdgcn_mfma_f32_16x16x32_f16(af, sv, acc[t], 0, 0, 0);
    }
    sv = cmbH(pB, cw);
#pragma unroll
    for (int t = 0; t < 2; t++) {
        f16x8 af = *(const f16x8*)(WpFo + (u32)(2 * TAP + 1) * 2048u + (u32)t * 512u + (u32)lane * 8u);
        acc[t] = __builtin_amdgcn_mfma_f32_16x16x32_f16(af, sv, acc[t], 0, 0, 0);
    }
    if constexpr (TAP < 8)
        tapB<TAP + 1>(win, moff, mmask, WpFo, p32, h, w, cb, quad, lane, pC, qn, wn, acc);
}

// ---------------------------------------------------------------------------
// Fused GEMM-a + GEMM-b, o-split waves. Block = 32 px, 256 thr = 4 waves =
// (pxg in {0,1}) x (oh in {0,1}). Window 7x38 staged swizzled; phase A
// computes o-rows oh*16..+16 (1 MFMA/step); strips in LDS; barrier; phase B
// computes o oh*32..+32 with 1-tap-lookahead pipelined LDS gathers.
// ---------------------------------------------------------------------------
__global__ __launch_bounds__(256, 4)
void gemm_ab_kernel(const u16* __restrict__ xt, const u16* __restrict__ W27F,
                    const u16* __restrict__ WpF,
                    const float* __restrict__ off_b, const float* __restrict__ mask_b,
                    u16* __restrict__ pre16, float* __restrict__ part) {
    __shared__ __align__(16) u16 win[(WPIX_ + 1) * 64];      // 34,176 B
    __shared__ float moff[18 * 32];                          //  2,304 B
    __shared__ float mmask[9 * 32];                          //  1,152 B
    const int tid = threadIdx.x;
    const int lane = tid & 63, wv = tid >> 6;    // 4 waves
    const int pxg = wv & 1, oh = wv >> 1;
    const u32 quad = (u32)(lane >> 4);
    const int r = lane & 15;
    const int pbase = blockIdx.x * 32;
    const int b = pbase >> 14, hwb = pbase & (HW_ - 1);
    const int h = hwb >> 7, w0 = hwb & (W_ - 1); // block = 32-px quarter-row
    const int p32 = pxg * 16 + r;
    const int hw = hwb + p32, w = w0 + p32;
    const int cb = (h - 3) * WCOLS_ + (w0 - 3);  // window origin
    const u32 bb = (u32)b << 14;

    // ---------------- stage window: 266 px x 128 B, coalesced, swizzled -----
#pragma unroll
    for (int it = 0; it < 9; it++) {
        int i = tid + it * 256;
        if (i < WPIX_ * 8) {
            u32 px = (u32)i >> 3, seg = (u32)i & 7u;
            int wr = (int)px / WCOLS_, wc = (int)px - wr * WCOLS_;
            int row = min(max(h - 3 + wr, 0), H_ - 1);
            int col = min(max(w0 - 3 + wc, 0), W_ - 1);
            u32 g = (bb + (u32)(row * W_ + col)) * 64u + seg * 8u;
            *(uint4*)(&win[swz(px, seg)]) = *(const uint4*)(xt + g);
        } else if (i < WPIX_ * 8 + 8) {          // zero slot px = 266
            u32 seg = (u32)(i - WPIX_ * 8);
            *(uint4*)(&win[swz((u32)WPIX_, seg)]) = make_uint4(0, 0, 0, 0);
        }
    }
    __syncthreads();

    // ---------------- Phase A: o-rows oh*16..+16, pipelined -----------------
    {
        u32 aq[9];
#pragma unroll
        for (int tap = 0; tap < 9; tap++) {
            int dh = tap / 3 - 1, dw = tap % 3 - 1;
            int hh = h + dh, ww = w + dw;
            bool valid = (hh >= 0) && (hh < H_) && (ww >= 0) && (ww < W_);
            u32 wpx = valid ? (u32)((3 + dh) * WCOLS_ + (p32 + 3 + dw)) : (u32)WPIX_;
            aq[tap] = swz(wpx, quad);
        }
        const u16* W27Fo = W27F + (u32)oh * 512u;
        f32x4 accA = (f32x4){0.f, 0.f, 0.f, 0.f};
        f16x8 ab[3];
        ab[0] = *(const f16x8*)(win + aq[0]);
        ab[1] = *(const f16x8*)(win + (aq[0] ^ 32u));
        ab[2] = *(const f16x8*)(win + aq[1]);
#pragma unroll
        for (int s = 0; s < 18; s++) {
            f16x8 sv = ab[s % 3];
            if (s + 3 < 18)
                ab[s % 3] = *(const f16x8*)(win + (aq[(s + 3) >> 1] ^ (u32)(((s + 3) & 1) * 32)));
            f16x8 af = *(const f16x8*)(W27Fo + (u32)s * 1024u + (u32)lane * 8u);
            accA = __builtin_amdgcn_mfma_f32_16x16x32_f16(af, sv, accA, 0, 0, 0);
        }
#pragma unroll
        for (int g = 0; g < 4; g++) {
            int o = oh * 16 + (int)quad * 4 + g;
            float v = accA[g];
            if (o < 18) {
                moff[o * 32 + p32] = v + off_b[o];
            } else if (o < 27) {
                v += mask_b[o - 18];
                mmask[(o - 18) * 32 + p32] = 1.f / (1.f + __expf(-v));
            }
        }
    }
    __syncthreads();

    // ---------------- Phase B: sampler GEMM, o oh*32..+32 -------------------
    f32x4 acc[2];
    acc[0] = (f32x4){0.f, 0.f, 0.f, 0.f};
    acc[1] = (f32x4){0.f, 0.f, 0.f, 0.f};
    {
        const u16* WpFo = WpF + (u32)oh * 1024u;
        u32 q[4]; u32 cw[4];
        metaBrt(moff, mmask, 0, p32, h, w, cb, quad, q, cw);
        uint4 pA[4];
        ld4x(win, q, 0, pA);
        tapB<0>(win, moff, mmask, WpFo, p32, h, w, cb, quad, lane, pA, q, cw, acc);
    }

    // ---------------- epilogue: bf16 pre-out + per-(block,pxg) stats --------
    const u32 slot = (u32)(blockIdx.x * 2 + pxg);
#pragma unroll
    for (int t = 0; t < 2; t++) {
#pragma unroll
        for (int g = 0; g < 4; g++) {
            float v = acc[t][g];
            int o = oh * 32 + t * 16 + (int)quad * 4 + g;
            pre16[(u32)(b * 64 + o) * HW_ + hw] = f2bf(v);
            float s = v, s2 = v * v;
#pragma unroll
            for (int off = 8; off >= 1; off >>= 1) {
                s  += __shfl_down(s, off, 16);
                s2 += __shfl_down(s2, off, 16);
            }
            if (r == 0) {
                part[(u32)o * 2048 + slot] = s;            // sums
                part[131072 + (u32)o * 2048 + slot] = s2;  // sumsqs
            }
        }
    }
}

// ---------------------------------------------------------------------------
// stats reduce: stats[i] (i<64 sum, i>=64 sumsq) = sum over 2048 contiguous
// partials (coalesced).
// ---------------------------------------------------------------------------
__global__ __launch_bounds__(256)
void stats_red_kernel(const float* __restrict__ part, float* __restrict__ stats) {
    __shared__ float p4[4];
    int i = blockIdx.x;                       // 0..127
    const float* src = part + (u32)(i >> 6) * 131072 + (u32)(i & 63) * 2048;
    float s = 0.f;
    for (int rr = threadIdx.x; rr < 2048; rr += 256) s += src[rr];
#pragma unroll
    for (int off = 32; off >= 1; off >>= 1) s += __shfl_down(s, off);
    if ((threadIdx.x & 63) == 0) p4[threadIdx.x >> 6] = s;
    __syncthreads();
    if (threadIdx.x == 0) stats[i] = p4[0] + p4[1] + p4[2] + p4[3];
}

// ---------------------------------------------------------------------------
// BN apply + ReLU from bf16 pre-out.
// ---------------------------------------------------------------------------
__global__ __launch_bounds__(256)
void bn_relu_kernel(const u16* __restrict__ pre16, const float* __restrict__ stats,
                    const float* __restrict__ gamma, const float* __restrict__ beta,
                    float* __restrict__ out) {
    int i4 = blockIdx.x * 256 + threadIdx.x;   // 4-element group index
    int ch = (i4 >> 12) & (O_ - 1);
    float mean = stats[ch] * (1.f / NPIX_);
    float var  = stats[64 + ch] * (1.f / NPIX_) - mean * mean;
    float scale = gamma[ch] * rsqrtf(var + BN_EPS_);
    float shift = beta[ch] - mean * scale;
    uint2 v = ((const uint2*)pre16)[i4];
    float4 o;
    o.x = fmaxf(fmaf(bflo(v.x), scale, shift), 0.f);
    o.y = fmaxf(fmaf(bfhi(v.x), scale, shift), 0.f);
    o.z = fmaxf(fmaf(bflo(v.y), scale, shift), 0.f);
    o.w = fmaxf(fmaf(bfhi(v.y), scale, shift), 0.f);
    ((float4*)out)[i4] = o;
}

// ---------------------------------------------------------------------------
extern "C" void kernel_launch(void* const* d_in, const int* in_sizes, int n_in,
                              void* d_out, int out_size, void* d_ws, size_t ws_size,
                              hipStream_t stream) {
    const float* x      = (const float*)d_in[0];
    const float* conv_w = (const float*)d_in[1];
    const float* off_w  = (const float*)d_in[2];
    const float* off_b  = (const float*)d_in[3];
    const float* mask_w = (const float*)d_in[4];
    const float* mask_b = (const float*)d_in[5];
    const float* gamma  = (const float*)d_in[6];
    const float* beta   = (const float*)d_in[7];
    float* out = (float*)d_out;

    // workspace layout: 9,548,416 B total
    char* ws = (char*)d_ws;
    u16*  xt     = (u16*)(ws);                   // [2][16384][64] f16 + pad = 4,194,432
    u16*  pre16  = (u16*)(ws + 4194432);         // [2][64][16384] bf16 = 4,194,304
    u16*  WpF    = (u16*)(ws + 8388736);         // 36,864 el = 73,728
    u16*  W27F   = (u16*)(ws + 8462464);         // 18,432 el = 36,864
    float* part  = (float*)(ws + 8499328);       // 2 x [64][2048] f32 = 1,048,576
    float* stats = (float*)(ws + 9547904);       // 128 f32 = 512

    prep_kernel<<<728, 256, 0, stream>>>(x, conv_w, off_w, mask_w, xt, WpF, W27F);
    gemm_ab_kernel<<<NPIX_ / 32, 256, 0, stream>>>(xt, W27F, WpF, off_b, mask_b, pre16, part);
    stats_red_kernel<<<128, 256, 0, stream>>>(part, stats);
    bn_relu_kernel<<<2048, 256, 0, stream>>>(pre16, stats, gamma, beta, out);
}